// Round 9
// baseline (453.933 us; speedup 1.0000x reference)
//
#include <hip/hip_runtime.h>

// GraphAttentionLayer: B=16, N=2048, F_IN=256, H=128 (fp32 in/out, adj int32)
//  k_pack: adj int32 -> 1 bit/entry, BLOCK-LINEAR read (DRAM-friendly; the
//          scattered per-row adj stream was measured at ~1.3 TB/s vs ~6 TB/s
//          linear). 268 MB -> 8.4 MB, L2/L3-resident afterwards.
//  k_wh  : MFMA bf16x3-split GEMM wh = X@W^T + bW; fused src/dst dots; writes
//          wh in MFMA B-FRAGMENT order whF[b][jc][ht][lane][8].
//  k_attn: barrier-free attention. Wave owns 16 i-rows x all 128 h. Per 32-j
//          chunk: packed bits (L2) -> exp weights -> A-frag in regs; B-frags
//          coalesced from whF (L2); 8 MFMAs. No LDS/barriers in loop.
//          Softmax normalization folded into epilogue (1/l scale).

#define BDIM 16
#define NDIM 2048
#define FIN 256
#define HDIM 128

typedef short short8 __attribute__((ext_vector_type(8)));
typedef float floatx4 __attribute__((ext_vector_type(4)));

__device__ __forceinline__ unsigned short f2bf(float x) {
    unsigned int u = __float_as_uint(x);
    unsigned int r = (u + 0x7fffu + ((u >> 16) & 1u)) >> 16;  // RNE
    return (unsigned short)r;
}
__device__ __forceinline__ float bf2f(unsigned short s) {
    return __uint_as_float(((unsigned int)s) << 16);
}

// ---------------- k_pack: adjacency bit-packing (linear stream) ----------------
// one thread per 32 consecutive entries; block covers 32 KB contiguous
__global__ __launch_bounds__(256) void k_pack(const int* __restrict__ adj,
                                              unsigned int* __restrict__ packed) {
    const size_t gid = (size_t)blockIdx.x * 256 + threadIdx.x;
    const int4* p = reinterpret_cast<const int4*>(adj + gid * 32);
    unsigned int bits = 0;
    #pragma unroll
    for (int k = 0; k < 8; k++) {
        int4 v = p[k];
        bits |= (v.x > 0 ? (1u << (4 * k + 0)) : 0u);
        bits |= (v.y > 0 ? (1u << (4 * k + 1)) : 0u);
        bits |= (v.z > 0 ? (1u << (4 * k + 2)) : 0u);
        bits |= (v.w > 0 ? (1u << (4 * k + 3)) : 0u);
    }
    packed[gid] = bits;
}

// ---------------- Kernel 1: wh via MFMA (bf16 hi/lo split) ----------------
// 64 rows x 128 h per block; 4 waves = 4 m-tiles of 16; K in panels of 64.
__global__ __launch_bounds__(256) void k_wh(const float* __restrict__ X,
                                            const float* __restrict__ W,
                                            const float* __restrict__ bW,
                                            const float* __restrict__ a,
                                            float* __restrict__ src,
                                            float* __restrict__ dst,
                                            unsigned short* __restrict__ whF) {
    __shared__ short lds[27648];                    // 54 KB
    short (*ah)[72] = (short(*)[72])lds;
    short (*al)[72] = (short(*)[72])(lds + 4608);
    short (*bh)[72] = (short(*)[72])(lds + 9216);
    short (*bl)[72] = (short(*)[72])(lds + 18432);
    short (*tb)[72] = (short(*)[72])lds;            // epilogue alias [128][72]

    const int tid = threadIdx.x;
    const long row0 = (long)blockIdx.x * 64;
    const int w = tid >> 6, lane = tid & 63;
    const int lm = lane & 15, q = lane >> 4;

    float a1v[8], a2v[8], bwv[8];
    #pragma unroll
    for (int nt = 0; nt < 8; nt++) {
        a1v[nt] = a[nt * 16 + lm];
        a2v[nt] = a[HDIM + nt * 16 + lm];
        bwv[nt] = bW[nt * 16 + lm];
    }

    floatx4 acc[8];
    #pragma unroll
    for (int nt = 0; nt < 8; nt++) acc[nt] = (floatx4){0.f, 0.f, 0.f, 0.f};

    for (int k0 = 0; k0 < FIN; k0 += 64) {
        #pragma unroll
        for (int u = 0; u < 4; u++) {
            int idx = tid + u * 256;
            int r = idx >> 4, fc = (idx & 15) * 4;
            float4 v = *reinterpret_cast<const float4*>(X + (row0 + r) * FIN + k0 + fc);
            union { unsigned short s[4]; uint2 u2; } ph, pl;
            ph.s[0] = f2bf(v.x); pl.s[0] = f2bf(v.x - bf2f(ph.s[0]));
            ph.s[1] = f2bf(v.y); pl.s[1] = f2bf(v.y - bf2f(ph.s[1]));
            ph.s[2] = f2bf(v.z); pl.s[2] = f2bf(v.z - bf2f(ph.s[2]));
            ph.s[3] = f2bf(v.w); pl.s[3] = f2bf(v.w - bf2f(ph.s[3]));
            *reinterpret_cast<uint2*>(&ah[r][fc]) = ph.u2;
            *reinterpret_cast<uint2*>(&al[r][fc]) = pl.u2;
        }
        #pragma unroll
        for (int u = 0; u < 8; u++) {
            int idx = tid + u * 256;
            int hh = idx >> 4, fc = (idx & 15) * 4;
            float4 v = *reinterpret_cast<const float4*>(W + hh * FIN + k0 + fc);
            union { unsigned short s[4]; uint2 u2; } ph, pl;
            ph.s[0] = f2bf(v.x); pl.s[0] = f2bf(v.x - bf2f(ph.s[0]));
            ph.s[1] = f2bf(v.y); pl.s[1] = f2bf(v.y - bf2f(ph.s[1]));
            ph.s[2] = f2bf(v.z); pl.s[2] = f2bf(v.z - bf2f(ph.s[2]));
            ph.s[3] = f2bf(v.w); pl.s[3] = f2bf(v.w - bf2f(ph.s[3]));
            *reinterpret_cast<uint2*>(&bh[hh][fc]) = ph.u2;
            *reinterpret_cast<uint2*>(&bl[hh][fc]) = pl.u2;
        }
        __syncthreads();
        #pragma unroll
        for (int ks = 0; ks < 64; ks += 32) {
            short8 afh = *reinterpret_cast<const short8*>(&ah[w * 16 + lm][ks + q * 8]);
            short8 afl = *reinterpret_cast<const short8*>(&al[w * 16 + lm][ks + q * 8]);
            #pragma unroll
            for (int nt = 0; nt < 8; nt++) {
                short8 bfh = *reinterpret_cast<const short8*>(&bh[nt * 16 + lm][ks + q * 8]);
                short8 bfl = *reinterpret_cast<const short8*>(&bl[nt * 16 + lm][ks + q * 8]);
                acc[nt] = __builtin_amdgcn_mfma_f32_16x16x32_bf16(afh, bfh, acc[nt], 0, 0, 0);
                acc[nt] = __builtin_amdgcn_mfma_f32_16x16x32_bf16(afh, bfl, acc[nt], 0, 0, 0);
                acc[nt] = __builtin_amdgcn_mfma_f32_16x16x32_bf16(afl, bfh, acc[nt], 0, 0, 0);
            }
        }
        __syncthreads();
    }

    // epilogue: bias, src/dst dots, transpose via LDS -> B-fragment layout
    float s1[4] = {0.f, 0.f, 0.f, 0.f}, s2[4] = {0.f, 0.f, 0.f, 0.f};
    #pragma unroll
    for (int nt = 0; nt < 8; nt++) {
        #pragma unroll
        for (int r = 0; r < 4; r++) {
            float v = acc[nt][r] + bwv[nt];
            s1[r] += v * a1v[nt];
            s2[r] += v * a2v[nt];
            tb[nt * 16 + lm][w * 16 + q * 4 + r] = f2bf(v);   // tb[h][jrel]
        }
    }
    #pragma unroll
    for (int r = 0; r < 4; r++) {
        #pragma unroll
        for (int o = 1; o < 16; o <<= 1) {
            s1[r] += __shfl_xor(s1[r], o);
            s2[r] += __shfl_xor(s2[r], o);
        }
    }
    if (lm == 0) {
        #pragma unroll
        for (int r = 0; r < 4; r++) {
            long row = row0 + w * 16 + q * 4 + r;
            src[row] = s1[r];
            dst[row] = s2[r];
        }
    }
    __syncthreads();
    // whF[b][jc][ht][l][e], frag = 512 shorts; block covers jc0..jc0+1
    const int b = (int)(row0 >> 11);
    const int jc0 = (int)((row0 & 2047) >> 5);
    const int f = tid >> 4;          // 0..15: jcrel = f>>3, ht = f&7
    const int sub = tid & 15;
    const int jcrel = f >> 3, ht = f & 7;
    const size_t fbase = (((size_t)b * 64 + jc0 + jcrel) * 8 + ht) * 512;
    #pragma unroll
    for (int i = 0; i < 4; i++) {
        int l = sub * 4 + i;
        uint4 v = *reinterpret_cast<const uint4*>(&tb[ht * 16 + (l & 15)][jcrel * 32 + (l >> 4) * 8]);
        *reinterpret_cast<uint4*>(whF + fbase + l * 8) = v;
    }
}

// ---------------- Kernel 2: barrier-free streaming MFMA attention ----------------
// 512 blocks; wave w owns i-rows i0+w*16..+15 (x all 128 h). No LDS/bar in loop.
// All loop operands (packed bits, dst, whF) are L2/L3-resident.
__global__ __launch_bounds__(256) void k_attn(const unsigned int* __restrict__ packed,
                                              const unsigned short* __restrict__ whF,
                                              const float* __restrict__ src,
                                              const float* __restrict__ dst,
                                              const float* __restrict__ ba_p,
                                              float* __restrict__ out) {
    __shared__ float lred[64];
    __shared__ float linv_s[64];

    const int tid = threadIdx.x;
    const int b = blockIdx.x >> 5;            // 32 i-tiles per batch
    const int i0 = (blockIdx.x & 31) * 64;
    const int wave = tid >> 6, lane = tid & 63;
    const int lm = lane & 15, q = lane >> 4;
    const int irow = i0 + wave * 16 + lm;

    const float si = src[b * NDIM + irow] + ba_p[0];
    const unsigned int* pk = packed + (size_t)(b * NDIM + irow) * (NDIM / 32);
    const float* dstp = dst + b * NDIM + q * 8;
    const unsigned short* whFb = whF + (size_t)b * 64 * 8 * 512 + lane * 8;

    floatx4 acc[8];
    #pragma unroll
    for (int hj = 0; hj < 8; hj++) acc[hj] = (floatx4){0.f, 0.f, 0.f, 0.f};
    float lpart = 0.f;

    unsigned int pw[2];
    float4 d[2][2];
    short8 bfr[2][8];
    // prefetch chunk 0 -> slot 0
    pw[0] = pk[0];
    d[0][0] = *reinterpret_cast<const float4*>(dstp);
    d[0][1] = *reinterpret_cast<const float4*>(dstp + 4);
    #pragma unroll
    for (int hj = 0; hj < 8; hj++) bfr[0][hj] = *reinterpret_cast<const short8*>(whFb + hj * 512);

    #pragma unroll 2
    for (int t = 0; t < NDIM / 32; t++) {
        const int p = t & 1, pn = p ^ 1;
        if (t + 1 < NDIM / 32) {   // issue next-chunk loads first (stay in flight)
            pw[pn] = pk[t + 1];
            const float* dp = dstp + (t + 1) * 32;
            d[pn][0] = *reinterpret_cast<const float4*>(dp);
            d[pn][1] = *reinterpret_cast<const float4*>(dp + 4);
            const unsigned short* wp = whFb + (size_t)(t + 1) * 8 * 512;
            #pragma unroll
            for (int hj = 0; hj < 8; hj++)
                bfr[pn][hj] = *reinterpret_cast<const short8*>(wp + hj * 512);
        }
        // A-frag: A[m=lm][k=q*8+j] = exp weight for (row irow, col t*32+q*8+j)
        const unsigned int byte = (pw[p] >> (q * 8)) & 0xffu;
        const float* df = reinterpret_cast<const float*>(&d[p][0]);
        unsigned short wb[8];
        float ls = 0.f;
        #pragma unroll
        for (int j = 0; j < 8; j++) {
            float x = si + df[j];
            x = x > 0.f ? x : 0.01f * x;
            float wgt = ((byte >> j) & 1u) ? __expf(x) : 0.f;
            ls += wgt;
            wb[j] = f2bf(wgt);
        }
        lpart += ls;
        short8 af = *reinterpret_cast<const short8*>(wb);
        #pragma unroll
        for (int hj = 0; hj < 8; hj++)
            acc[hj] = __builtin_amdgcn_mfma_f32_16x16x32_bf16(af, bfr[p][hj], acc[hj], 0, 0, 0);
    }

    // denominator: combine the 4 q-slices of each row
    lpart += __shfl_xor(lpart, 16);
    lpart += __shfl_xor(lpart, 32);
    if (q == 0) lred[wave * 16 + lm] = lpart;
    __syncthreads();
    if (tid < 64) {
        float l = lred[tid];
        linv_s[tid] = l > 0.f ? 1.f / l : 0.f;
    }
    __syncthreads();

    // epilogue: scale 1/l, ELU, store (C/D: col=lm -> h, row=q*4+r -> i)
    #pragma unroll
    for (int r = 0; r < 4; r++) {
        int il = wave * 16 + q * 4 + r;
        float li = linv_s[il];
        size_t obase = ((size_t)(b * NDIM + i0 + il)) * HDIM + lm;
        #pragma unroll
        for (int hj = 0; hj < 8; hj++) {
            float x = acc[hj][r] * li;
            x = x > 0.f ? x : (__expf(x) - 1.f);
            out[obase + hj * 16] = x;
        }
    }
}

extern "C" void kernel_launch(void* const* d_in, const int* in_sizes, int n_in,
                              void* d_out, int out_size, void* d_ws, size_t ws_size,
                              hipStream_t stream) {
    const float* X  = (const float*)d_in[0];   // [16,2048,256]
    const int* adj  = (const int*)d_in[1];     // [16,2048,2048]
    const float* W  = (const float*)d_in[2];   // [128,256]
    const float* bW = (const float*)d_in[3];   // [128]
    const float* a  = (const float*)d_in[4];   // [1,256]
    const float* ba = (const float*)d_in[5];   // [1]
    float* out = (float*)d_out;                // [16,2048,128]

    float* srcv = (float*)d_ws;                                    // B*N
    float* dstv = srcv + BDIM * NDIM;                              // B*N
    unsigned short* whF = (unsigned short*)(dstv + BDIM * NDIM);   // 8.4 MB bf16 frag-order
    unsigned int* packed = (unsigned int*)(whF + (size_t)BDIM * HDIM * NDIM);  // 8.4 MB bits

    k_pack<<<(BDIM * NDIM * (NDIM / 32)) / 256, 256, 0, stream>>>(adj, packed);
    k_wh<<<BDIM * NDIM / 64, 256, 0, stream>>>(X, W, bW, a, srcv, dstv, whF);
    k_attn<<<BDIM * (NDIM / 64), 256, 0, stream>>>(packed, whF, srcv, dstv, ba, out);
}